// Round 2
// baseline (812.968 us; speedup 1.0000x reference)
//
#include <hip/hip_runtime.h>
#include <hip/hip_fp16.h>
#include <stdint.h>

#define TOKENS 4096
#define IN_F   4096
#define OUT_F  11008

#define BM  128
#define BN  128
#define BK  32
#define LDT 40            // padded LDS row stride in halves (32 + 8); 80B = odd multiple of 16B
#define NKT (IN_F / BK)   // 128 K-tiles

typedef _Float16 half8 __attribute__((ext_vector_type(8)));
typedef float    f32x4 __attribute__((ext_vector_type(4)));

union H4 { __half2 h2[2]; uint2 u2; };
union H8 { __half2 h2[4]; uint4 u4; };

// One int32 holds one packed byte (harness uploads integer inputs as int32).
// low nibble = even k, high nibble = odd k. Returns dequantized half2 (k_even, k_odd).
__device__ inline __half2 dequant_byte(int v, __half2 s2, __half2 b2) {
  float lo = (float)(v & 15);
  float hi = (float)((v >> 4) & 15);
  return __hfma2(__floats2half2_rn(lo, hi), s2, b2);
}

__global__ __launch_bounds__(256, 2)
void int4_gemm_kernel(const float* __restrict__ x,
                      const int* __restrict__ wq,
                      const float* __restrict__ scale,
                      const float* __restrict__ zero,
                      float* __restrict__ out)
{
  __shared__ __half As[BM * LDT];
  __shared__ __half Bs[BN * LDT];

  const int tid  = threadIdx.x;
  const int n0   = blockIdx.x * BN;   // 0..85 * 128
  const int m0   = blockIdx.y * BM;   // 0..31 * 128
  const int lane = tid & 63;
  const int wave = tid >> 6;          // 0..3
  const int wm   = (wave >> 1) * 64;  // wave row offset in tile
  const int wn   = (wave & 1) * 64;   // wave col offset in tile

  // ---- B staging assignment: fixed weight row per thread across whole K loop ----
  const int rowb  = tid >> 1;         // 0..127
  const int bhalf = tid & 1;          // which 16-k half of the 32-k slab
  const float s = scale[n0 + rowb];
  const float z = zero[n0 + rowb];
  const __half2 s2 = __floats2half2_rn(s, s);
  const float   nb = -z * s;          // bias in fp32 (avoid correlated per-row error)
  const __half2 b2 = __floats2half2_rn(nb, nb);
  // int32 elements; IN_F/2 per row; 16 per row per K-tile; this thread: 8 starting at bhalf*8
  const int* wp = wq + (size_t)(n0 + rowb) * (IN_F / 2) + bhalf * 8;

  // ---- A staging assignment: 4 float4 loads per thread per K-tile ----
  const float* xp[4];
  int arow[4], ac4[4];
#pragma unroll
  for (int i = 0; i < 4; ++i) {
    int idx = tid + i * 256;          // 0..1023
    arow[i] = idx >> 3;               // 0..127
    ac4[i]  = idx & 7;                // float4 index within 32-wide k slab
    xp[i] = x + (size_t)(m0 + arow[i]) * IN_F + ac4[i] * 4;
  }

  f32x4 acc[4][4];
#pragma unroll
  for (int i = 0; i < 4; ++i)
#pragma unroll
    for (int j = 0; j < 4; ++j)
      acc[i][j] = (f32x4){0.f, 0.f, 0.f, 0.f};

  // prefetch K-tile 0 into registers
  float4 apf[4];
  int4   bpf0, bpf1;
#pragma unroll
  for (int i = 0; i < 4; ++i) apf[i] = *(const float4*)(xp[i]);
  bpf0 = *(const int4*)(wp);
  bpf1 = *(const int4*)(wp + 4);

  for (int kt = 0; kt < NKT; ++kt) {
    // ---- stage A: fp32 -> f16 -> LDS (ds_write_b64) ----
#pragma unroll
    for (int i = 0; i < 4; ++i) {
      H4 t;
      t.h2[0] = __floats2half2_rn(apf[i].x, apf[i].y);
      t.h2[1] = __floats2half2_rn(apf[i].z, apf[i].w);
      *reinterpret_cast<uint2*>(&As[arow[i] * LDT + ac4[i] * 4]) = t.u2;
    }
    // ---- stage B: dequant 8 bytes (16 nibbles) -> LDS (2x ds_write_b128) ----
    {
      H8 r0, r1;
      r0.h2[0] = dequant_byte(bpf0.x, s2, b2);
      r0.h2[1] = dequant_byte(bpf0.y, s2, b2);
      r0.h2[2] = dequant_byte(bpf0.z, s2, b2);
      r0.h2[3] = dequant_byte(bpf0.w, s2, b2);
      r1.h2[0] = dequant_byte(bpf1.x, s2, b2);
      r1.h2[1] = dequant_byte(bpf1.y, s2, b2);
      r1.h2[2] = dequant_byte(bpf1.z, s2, b2);
      r1.h2[3] = dequant_byte(bpf1.w, s2, b2);
      *reinterpret_cast<uint4*>(&Bs[rowb * LDT + bhalf * 16 + 0]) = r0.u4;
      *reinterpret_cast<uint4*>(&Bs[rowb * LDT + bhalf * 16 + 8]) = r1.u4;
    }
    // ---- register prefetch of next K-tile (in flight across the MFMA section) ----
    if (kt + 1 < NKT) {
#pragma unroll
      for (int i = 0; i < 4; ++i) apf[i] = *(const float4*)(xp[i] + (kt + 1) * BK);
      bpf0 = *(const int4*)(wp + (size_t)(kt + 1) * 16);
      bpf1 = *(const int4*)(wp + (size_t)(kt + 1) * 16 + 4);
    }
    __syncthreads();

    // ---- fragment reads + MFMA ----
    const int fm = lane & 15;
    const int q4 = lane >> 4;
    half8 af[4], bf[4];
#pragma unroll
    for (int i = 0; i < 4; ++i)
      af[i] = *reinterpret_cast<const half8*>(&As[(wm + i * 16 + fm) * LDT + q4 * 8]);
#pragma unroll
    for (int j = 0; j < 4; ++j)
      bf[j] = *reinterpret_cast<const half8*>(&Bs[(wn + j * 16 + fm) * LDT + q4 * 8]);
#pragma unroll
    for (int i = 0; i < 4; ++i)
#pragma unroll
      for (int j = 0; j < 4; ++j)
        acc[i][j] = __builtin_amdgcn_mfma_f32_16x16x32_f16(af[i], bf[j], acc[i][j], 0, 0, 0);
    __syncthreads();
  }

  // ---- epilogue: C/D layout col=lane&15 (n), row=(lane>>4)*4+reg (m) ----
  const int col = lane & 15;
  const int r0q = (lane >> 4) * 4;
#pragma unroll
  for (int i = 0; i < 4; ++i) {
#pragma unroll
    for (int j = 0; j < 4; ++j) {
#pragma unroll
      for (int r = 0; r < 4; ++r) {
        const int m = m0 + wm + i * 16 + r0q + r;
        const int n = n0 + wn + j * 16 + col;
        out[(size_t)m * OUT_F + n] = acc[i][j][r];
      }
    }
  }
}

extern "C" void kernel_launch(void* const* d_in, const int* in_sizes, int n_in,
                              void* d_out, int out_size, void* d_ws, size_t ws_size,
                              hipStream_t stream) {
  const float* x     = (const float*)d_in[0];
  const int*   wq    = (const int*)d_in[1];     // integer inputs arrive as int32
  const float* scale = (const float*)d_in[2];
  const float* zero  = (const float*)d_in[3];
  float* out = (float*)d_out;

  dim3 grid(OUT_F / BN, TOKENS / BM);   // 86 x 32 = 2752 blocks
  int4_gemm_kernel<<<grid, 256, 0, stream>>>(x, wq, scale, zero, out);
}